// Round 1
// baseline (590.802 us; speedup 1.0000x reference)
//
#include <hip/hip_runtime.h>

// ---------- types ----------
typedef unsigned short u16;
typedef __attribute__((ext_vector_type(4))) unsigned short u16x4;
typedef __attribute__((ext_vector_type(8))) unsigned short u16x8;
typedef __attribute__((ext_vector_type(8))) short bf16x8;   // 8 bf16 = 4 VGPRs
typedef __attribute__((ext_vector_type(4))) float f32x4;

#define LORA_SCALE 2.0f   // ALPHA/RANK = 32/16

// round-to-nearest-even f32 -> bf16 (inputs are finite normals; NaN path not needed)
__device__ __forceinline__ u16 f2bf(float f) {
  unsigned u = __builtin_bit_cast(unsigned, f);
  u += 0x7FFFu + ((u >> 16) & 1u);
  return (u16)(u >> 16);
}

#define GLOAD16(g, l) __builtin_amdgcn_global_load_lds(                        \
    (const __attribute__((address_space(1))) void*)(g),                        \
    (__attribute__((address_space(3))) void*)(l), 16, 0, 0)

// ---------------------------------------------------------------------------
// Kernel 1: W_eff[n,k] = W[n,k] + SCALE * sum_r B[k,r]*A[r,n]  -> bf16
// W: [4096,4096] row-major (n,k). B: [4096,16] (k,r). A: [16,4096] (r,n).
// grid = (N/64)*(K/256) = 64*16 = 1024 blocks, 256 threads.
// ---------------------------------------------------------------------------
__global__ __launch_bounds__(256) void make_weff(
    const float* __restrict__ W, const float* __restrict__ B,
    const float* __restrict__ A, u16* __restrict__ Wb)
{
  __shared__ float sA[16][64];              // SCALE * A[r][n0+j]
  const int n0 = (blockIdx.x >> 4) * 64;    // 64 n-tiles
  const int k0 = (blockIdx.x & 15) * 256;   // 16 k-tiles
  const int t  = threadIdx.x;

  { // stage scaled A column block: 16x64 f32, 4 per thread
    const int r = t >> 4;
    const int j = (t & 15) * 4;
    const float4 v = *(const float4*)(A + (size_t)r * 4096 + n0 + j);
    sA[r][j + 0] = LORA_SCALE * v.x;
    sA[r][j + 1] = LORA_SCALE * v.y;
    sA[r][j + 2] = LORA_SCALE * v.z;
    sA[r][j + 3] = LORA_SCALE * v.w;
  }
  __syncthreads();

  const int tn = t >> 6;    // 0..3 (wave-uniform)
  const int tk = t & 63;    // lane

  // B rows for this thread's 4 k values: 64 consecutive f32, kept in regs
  float bv[64];
  const float4* pb = (const float4*)(B + (size_t)(k0 + tk * 4) * 16);
#pragma unroll
  for (int q = 0; q < 16; ++q) {
    float4 v = pb[q];
    bv[q * 4 + 0] = v.x; bv[q * 4 + 1] = v.y;
    bv[q * 4 + 2] = v.z; bv[q * 4 + 3] = v.w;
  }
  // bv[j*16+r] = B[(k0+tk*4+j)*16 + r]

  for (int i = 0; i < 16; ++i) {
    const int n = n0 + tn * 16 + i;
    const float4 w4 = *(const float4*)(W + (size_t)n * 4096 + k0 + tk * 4);
    float acc[4] = {w4.x, w4.y, w4.z, w4.w};
#pragma unroll
    for (int j = 0; j < 4; ++j)
#pragma unroll
      for (int r = 0; r < 16; ++r)
        acc[j] += bv[j * 16 + r] * sA[r][tn * 16 + i];   // sA read is broadcast
    u16x4 o;
    o[0] = f2bf(acc[0]); o[1] = f2bf(acc[1]);
    o[2] = f2bf(acc[2]); o[3] = f2bf(acc[3]);
    *(u16x4*)(Wb + (size_t)n * 4096 + k0 + tk * 4) = o;
  }
}

// ---------------------------------------------------------------------------
// Kernel 2: x f32 -> bf16 (33.55M elems), vectorized 8/thread/iter
// ---------------------------------------------------------------------------
__global__ __launch_bounds__(256) void cvt_x_kernel(
    const float* __restrict__ x, u16* __restrict__ xb, long n)
{
  long i0 = ((long)blockIdx.x * blockDim.x + threadIdx.x) * 8;
  long stride = (long)gridDim.x * blockDim.x * 8;
  for (long i = i0; i < n; i += stride) {
    float4 a = *(const float4*)(x + i);
    float4 b = *(const float4*)(x + i + 4);
    u16x8 o;
    o[0] = f2bf(a.x); o[1] = f2bf(a.y); o[2] = f2bf(a.z); o[3] = f2bf(a.w);
    o[4] = f2bf(b.x); o[5] = f2bf(b.y); o[6] = f2bf(b.z); o[7] = f2bf(b.w);
    *(u16x8*)(xb + i) = o;
  }
}

// ---------------------------------------------------------------------------
// Kernel 3: out[m,n] = sum_k Xb[m,k]*Wb[n,k] + bias[n]   (bf16 MFMA, f32 out)
// m97 structure: 128x128 tile, BK=64, 256 thr (4 waves, 2x2), wave = 64x64,
// 4x4 frags of 16x16x32, global_load_lds width 16, single LDS buffer.
// grid = (8192/128)*(4096/128) = 64*32 = 2048 blocks.
// ---------------------------------------------------------------------------
#define BM 128
#define BN 128
#define BKK 64

__global__ __launch_bounds__(256) void gemm_bias(
    const u16* __restrict__ Xb, const u16* __restrict__ Wb,
    const float* __restrict__ bias, float* __restrict__ out)
{
  const int K = 4096, N = 4096;
  __shared__ u16 sA[BM][BKK];   // 16 KB
  __shared__ u16 sB[BN][BKK];   // 16 KB

  const int t  = threadIdx.x;
  const int l  = t & 63;
  const int w  = t >> 6;        // 0..3
  const int wr = w >> 1;        // wave row (0..1) -> 64 rows
  const int wc = w & 1;         // wave col (0..1) -> 64 cols

  const int ntn = N / BN;       // 32
  const int tm = blockIdx.x / ntn, tn = blockIdx.x % ntn;
  const int m0 = tm * BM, n0 = tn * BN;

  // staging: LDS flat byte f = c*4096 + t*16 -> row = c*32 + t/8, colelem = (t&7)*8
  const int srow = t >> 3;
  const int scol = (t & 7) * 8;
  const u16* gA = Xb + (size_t)(m0 + srow) * K + scol;
  const u16* gB = Wb + (size_t)(n0 + srow) * K + scol;
  char* lA = (char*)(&sA[0][0]) + t * 16;
  char* lB = (char*)(&sB[0][0]) + t * 16;

  f32x4 acc[4][4];
#pragma unroll
  for (int i = 0; i < 4; ++i)
#pragma unroll
    for (int j = 0; j < 4; ++j) acc[i][j] = (f32x4){0.f, 0.f, 0.f, 0.f};

  const int fr = l & 15;        // fragment row/col index
  const int fq = l >> 4;        // quad 0..3

  for (int kt = 0; kt < K; kt += BKK) {
#pragma unroll
    for (int c = 0; c < 4; ++c) {
      GLOAD16(gA + (size_t)(c * 32) * K + kt, lA + c * 4096);
      GLOAD16(gB + (size_t)(c * 32) * K + kt, lB + c * 4096);
    }
    asm volatile("s_waitcnt vmcnt(0)" ::: "memory");
    __syncthreads();

#pragma unroll
    for (int ks = 0; ks < BKK; ks += 32) {
      bf16x8 af[4], bfr[4];
#pragma unroll
      for (int mi = 0; mi < 4; ++mi)
        af[mi] = *(const bf16x8*)&sA[wr * 64 + mi * 16 + fr][ks + fq * 8];
#pragma unroll
      for (int nj = 0; nj < 4; ++nj)
        bfr[nj] = *(const bf16x8*)&sB[wc * 64 + nj * 16 + fr][ks + fq * 8];
#pragma unroll
      for (int mi = 0; mi < 4; ++mi)
#pragma unroll
        for (int nj = 0; nj < 4; ++nj)
          acc[mi][nj] = __builtin_amdgcn_mfma_f32_16x16x32_bf16(
              af[mi], bfr[nj], acc[mi][nj], 0, 0, 0);
    }
    __syncthreads();
  }

  // epilogue: C/D layout col = lane&15, row = (lane>>4)*4 + i  (guide-verified)
  float bvals[4];
#pragma unroll
  for (int nj = 0; nj < 4; ++nj) bvals[nj] = bias[n0 + wc * 64 + nj * 16 + fr];

#pragma unroll
  for (int mi = 0; mi < 4; ++mi) {
#pragma unroll
    for (int i = 0; i < 4; ++i) {
      const int m = m0 + wr * 64 + mi * 16 + fq * 4 + i;
      float* orow = out + (size_t)m * N + n0 + wc * 64 + fr;
#pragma unroll
      for (int nj = 0; nj < 4; ++nj)
        orow[nj * 16] = acc[mi][nj][i] + bvals[nj];
    }
  }
}

// ---------------------------------------------------------------------------
extern "C" void kernel_launch(void* const* d_in, const int* in_sizes, int n_in,
                              void* d_out, int out_size, void* d_ws, size_t ws_size,
                              hipStream_t stream) {
  const float* x    = (const float*)d_in[0];  // [4,2048,4096] -> [8192,4096]
  const float* W    = (const float*)d_in[1];  // [4096,4096] (n,k)
  const float* bias = (const float*)d_in[2];  // [4096]
  const float* B    = (const float*)d_in[3];  // [4096,16]
  const float* A    = (const float*)d_in[4];  // [16,4096]
  float* out = (float*)d_out;

  u16* Xb = (u16*)d_ws;                         // 8192*4096 bf16 = 64 MiB
  u16* Wb = Xb + (size_t)8192 * 4096;           // 4096*4096 bf16 = 32 MiB

  make_weff<<<dim3(1024), dim3(256), 0, stream>>>(W, B, A, Wb);
  cvt_x_kernel<<<dim3(2048), dim3(256), 0, stream>>>(x, Xb, (long)8192 * 4096);
  gemm_bias<<<dim3(2048), dim3(256), 0, stream>>>(Xb, Wb, bias, out);
}

// Round 3
// 516.943 us; speedup vs baseline: 1.1429x; 1.1429x over previous
//
#include <hip/hip_runtime.h>

// ---------- types ----------
typedef unsigned short u16;
typedef __attribute__((ext_vector_type(4))) unsigned short u16x4;
typedef __attribute__((ext_vector_type(8))) unsigned short u16x8;
typedef __attribute__((ext_vector_type(8))) short bf16x8;   // 8 bf16 = 4 VGPRs
typedef __attribute__((ext_vector_type(4))) float f32x4;

#define LORA_SCALE 2.0f   // ALPHA/RANK = 32/16

// round-to-nearest-even f32 -> bf16
__device__ __forceinline__ u16 f2bf(float f) {
  unsigned u = __builtin_bit_cast(unsigned, f);
  u += 0x7FFFu + ((u >> 16) & 1u);
  return (u16)(u >> 16);
}

#define GLOAD16(g, l) __builtin_amdgcn_global_load_lds(                        \
    (const __attribute__((address_space(1))) void*)(g),                        \
    (__attribute__((address_space(3))) void*)(l), 16, 0, 0)

// ---------------------------------------------------------------------------
// Kernel 1: W_eff[n,k] = W[n,k] + SCALE * sum_r B[k,r]*A[r,n]  -> bf16
// ---------------------------------------------------------------------------
__global__ __launch_bounds__(256) void make_weff(
    const float* __restrict__ W, const float* __restrict__ B,
    const float* __restrict__ A, u16* __restrict__ Wb)
{
  __shared__ float sA[16][64];
  const int n0 = (blockIdx.x >> 4) * 64;
  const int k0 = (blockIdx.x & 15) * 256;
  const int t  = threadIdx.x;

  {
    const int r = t >> 4;
    const int j = (t & 15) * 4;
    const float4 v = *(const float4*)(A + (size_t)r * 4096 + n0 + j);
    sA[r][j + 0] = LORA_SCALE * v.x;
    sA[r][j + 1] = LORA_SCALE * v.y;
    sA[r][j + 2] = LORA_SCALE * v.z;
    sA[r][j + 3] = LORA_SCALE * v.w;
  }
  __syncthreads();

  const int tn = t >> 6;
  const int tk = t & 63;

  float bv[64];
  const float4* pb = (const float4*)(B + (size_t)(k0 + tk * 4) * 16);
#pragma unroll
  for (int q = 0; q < 16; ++q) {
    float4 v = pb[q];
    bv[q * 4 + 0] = v.x; bv[q * 4 + 1] = v.y;
    bv[q * 4 + 2] = v.z; bv[q * 4 + 3] = v.w;
  }

  for (int i = 0; i < 16; ++i) {
    const int n = n0 + tn * 16 + i;
    const float4 w4 = *(const float4*)(W + (size_t)n * 4096 + k0 + tk * 4);
    float acc[4] = {w4.x, w4.y, w4.z, w4.w};
#pragma unroll
    for (int j = 0; j < 4; ++j)
#pragma unroll
      for (int r = 0; r < 16; ++r)
        acc[j] += bv[j * 16 + r] * sA[r][tn * 16 + i];
    u16x4 o;
    o[0] = f2bf(acc[0]); o[1] = f2bf(acc[1]);
    o[2] = f2bf(acc[2]); o[3] = f2bf(acc[3]);
    *(u16x4*)(Wb + (size_t)n * 4096 + k0 + tk * 4) = o;
  }
}

// ---------------------------------------------------------------------------
// Kernel 2: x f32 -> bf16
// ---------------------------------------------------------------------------
__global__ __launch_bounds__(256) void cvt_x_kernel(
    const float* __restrict__ x, u16* __restrict__ xb, long n)
{
  long i0 = ((long)blockIdx.x * blockDim.x + threadIdx.x) * 8;
  long stride = (long)gridDim.x * blockDim.x * 8;
  for (long i = i0; i < n; i += stride) {
    float4 a = *(const float4*)(x + i);
    float4 b = *(const float4*)(x + i + 4);
    u16x8 o;
    o[0] = f2bf(a.x); o[1] = f2bf(a.y); o[2] = f2bf(a.z); o[3] = f2bf(a.w);
    o[4] = f2bf(b.x); o[5] = f2bf(b.y); o[6] = f2bf(b.z); o[7] = f2bf(b.w);
    *(u16x8*)(xb + i) = o;
  }
}

// ---------------------------------------------------------------------------
// Kernel 3: 256x256 tile, BK=32, 512 thr (8 waves 2Mx4N, 128x64 per wave),
// TRIPLE-buffered LDS (3 x 32KB), 2 phases/tile x 16 MFMA, counted vmcnt(4),
// raw s_barrier, setprio around MFMA, XOR-swizzled LDS (pre-swizzled source),
// XCD-bijective block swizzle. Race-free by construction:
//   tile T computes buf T%3; issues tile T+2 into buf (T+2)%3 == (T-1)%3,
//   whose readers (tile T-1) are all behind the tile-(T-1)-end barrier.
// grid = (8192/256)*(4096/256) = 32*16 = 512 blocks.
// R2 bug: buffer rotation wrapped at 1 (0->1->0...), so tiles >=2 read
// stale/wrong buffers. Fixed: wrap at 2 (0->1->2->0...). Nothing else changed.
// ---------------------------------------------------------------------------
__global__ __launch_bounds__(512, 2) void gemm256(
    const u16* __restrict__ Xb, const u16* __restrict__ Wb,
    const float* __restrict__ bias, float* __restrict__ out)
{
  constexpr int K = 4096, N = 4096;
  constexpr int NT = K / 32;            // 128 K-tiles
  __shared__ char lds[3 * 32768];       // per buf: A 16KB @0, B 16KB @16384

  const int t = threadIdx.x;
  const int w = t >> 6, l = t & 63;
  const int wave_m = w >> 2, wave_n = w & 3;

  // XCD-bijective swizzle (512 % 8 == 0)
  const int bid = blockIdx.x;
  const int swz = (bid & 7) * 64 + (bid >> 3);
  const int tm = swz >> 4, tn = swz & 15;       // 32 x 16 tiles
  const int m0 = tm * 256, n0 = tn * 256;

  // ---- staging addressing (pre-swizzled global source, linear LDS dest) ----
  // LDS flat (row r, 16B-chunk c'):  r*64 + c'*16 ; content = global chunk c'^s(r),
  // s(r) = (r>>1)&3.  lane l -> r_local = l>>2, c' = l&3, source chunk = (l&3)^((l>>3)&3).
  const int lrow = l >> 2;
  const int lch  = ((l & 3) ^ ((l >> 3) & 3)) * 8;   // element offset in K
  const u16* gAs = Xb + (size_t)(m0 + w * 16 + lrow) * K + lch;
  const u16* gBs = Wb + (size_t)(n0 + w * 16 + lrow) * K + lch;
  char* ldsw = lds + w * 1024;                       // wave-uniform dest base

#define STAGE_A(tt, bb) do {                                                   \
    GLOAD16(gAs + (size_t)(tt) * 32,                  ldsw + (bb) * 32768);    \
    GLOAD16(gAs + (size_t)(tt) * 32 + 128 * (size_t)K, ldsw + (bb) * 32768 + 8192); \
  } while (0)
#define STAGE_B(tt, bb) do {                                                   \
    GLOAD16(gBs + (size_t)(tt) * 32,                  ldsw + (bb) * 32768 + 16384); \
    GLOAD16(gBs + (size_t)(tt) * 32 + 128 * (size_t)K, ldsw + (bb) * 32768 + 16384 + 8192); \
  } while (0)

  // ---- fragment read bases (swizzled chunk: fq ^ ((fr>>1)&3)) ----
  const int fr = l & 15, fq = l >> 4;
  const int coff = (fq ^ ((fr >> 1) & 3)) << 4;      // byte offset of chunk
  const char* pa0 = lds + (wave_m * 128 + fr) * 64 + coff;
  const char* pb0 = lds + 16384 + (wave_n * 64 + fr) * 64 + coff;

  f32x4 acc[8][4];
#pragma unroll
  for (int i = 0; i < 8; ++i)
#pragma unroll
    for (int j = 0; j < 4; ++j) acc[i][j] = (f32x4){0.f, 0.f, 0.f, 0.f};

  // ---- prologue: tiles 0,1 in flight; wait tile 0 ----
  STAGE_A(0, 0); STAGE_B(0, 0);
  STAGE_A(1, 1); STAGE_B(1, 1);
  asm volatile("s_waitcnt vmcnt(4)" ::: "memory");
  __builtin_amdgcn_s_barrier();

  int b = 0;
  for (int tt = 0; tt < NT; ++tt) {
    const char* pa = pa0 + b * 32768;
    const char* pb = pb0 + b * 32768;
    const int bs = (b == 2) ? 0 : b + 1;   // (tt+1)%3  [R2 bug was wrap at 1]
    const int b2 = (b >= 1) ? b - 1 : 2;   // (tt+2)%3

    // ---------- phase A: rows 0-63 of this wave's 128 ----------
    bf16x8 bf[4], af[4];
#pragma unroll
    for (int nj = 0; nj < 4; ++nj)
      bf[nj] = *(const bf16x8*)(pb + nj * 1024);
#pragma unroll
    for (int mi = 0; mi < 4; ++mi)
      af[mi] = *(const bf16x8*)(pa + mi * 1024);
    if (tt + 2 < NT) STAGE_A(tt + 2, b2);
    __builtin_amdgcn_s_barrier();
    __builtin_amdgcn_s_setprio(1);
#pragma unroll
    for (int mi = 0; mi < 4; ++mi)
#pragma unroll
      for (int nj = 0; nj < 4; ++nj)
        acc[mi][nj] = __builtin_amdgcn_mfma_f32_16x16x32_bf16(
            af[mi], bf[nj], acc[mi][nj], 0, 0, 0);
    __builtin_amdgcn_s_setprio(0);
    __builtin_amdgcn_s_barrier();

    // ---------- phase B: rows 64-127 (B frags reused from regs) ----------
#pragma unroll
    for (int mi = 0; mi < 4; ++mi)
      af[mi] = *(const bf16x8*)(pa + 4096 + mi * 1024);
    if (tt + 2 < NT) STAGE_B(tt + 2, b2);
    __builtin_amdgcn_s_barrier();
    __builtin_amdgcn_s_setprio(1);
#pragma unroll
    for (int mi = 0; mi < 4; ++mi)
#pragma unroll
      for (int nj = 0; nj < 4; ++nj)
        acc[4 + mi][nj] = __builtin_amdgcn_mfma_f32_16x16x32_bf16(
            af[mi], bf[nj], acc[4 + mi][nj], 0, 0, 0);
    __builtin_amdgcn_s_setprio(0);
    // counted vmcnt: allow tile tt+2's 4 loads in flight, force tile tt+1 landed
    if (tt + 2 < NT) { asm volatile("s_waitcnt vmcnt(4)" ::: "memory"); }
    else             { asm volatile("s_waitcnt vmcnt(0)" ::: "memory"); }
    __builtin_amdgcn_s_barrier();

    b = bs;
  }

  // ---- epilogue: bias + store (C/D layout: col=lane&15, row=(lane>>4)*4+i) ----
  float bvals[4];
#pragma unroll
  for (int nj = 0; nj < 4; ++nj)
    bvals[nj] = bias[n0 + wave_n * 64 + nj * 16 + fr];

#pragma unroll
  for (int ph = 0; ph < 2; ++ph)
#pragma unroll
    for (int mi = 0; mi < 4; ++mi)
#pragma unroll
      for (int i = 0; i < 4; ++i) {
        const int m = m0 + wave_m * 128 + ph * 64 + mi * 16 + fq * 4 + i;
        float* orow = out + (size_t)m * N + n0 + wave_n * 64 + fr;
#pragma unroll
        for (int nj = 0; nj < 4; ++nj)
          orow[nj * 16] = acc[ph * 4 + mi][nj][i] + bvals[nj];
      }
}

// ---------------------------------------------------------------------------
extern "C" void kernel_launch(void* const* d_in, const int* in_sizes, int n_in,
                              void* d_out, int out_size, void* d_ws, size_t ws_size,
                              hipStream_t stream) {
  const float* x    = (const float*)d_in[0];  // [4,2048,4096] -> [8192,4096]
  const float* W    = (const float*)d_in[1];  // [4096,4096] (n,k)
  const float* bias = (const float*)d_in[2];  // [4096]
  const float* B    = (const float*)d_in[3];  // [4096,16]
  const float* A    = (const float*)d_in[4];  // [16,4096]
  float* out = (float*)d_out;

  u16* Xb = (u16*)d_ws;                         // 8192*4096 bf16 = 64 MiB
  u16* Wb = Xb + (size_t)8192 * 4096;           // 4096*4096 bf16 = 32 MiB

  make_weff<<<dim3(1024), dim3(256), 0, stream>>>(W, B, A, Wb);
  cvt_x_kernel<<<dim3(2048), dim3(256), 0, stream>>>(x, Xb, (long)8192 * 4096);
  gemm256<<<dim3(512), dim3(512), 0, stream>>>(Xb, Wb, bias, out);
}

// Round 4
// 510.476 us; speedup vs baseline: 1.1574x; 1.0127x over previous
//
#include <hip/hip_runtime.h>

// ---------- types ----------
typedef unsigned short u16;
typedef __attribute__((ext_vector_type(4))) unsigned short u16x4;
typedef __attribute__((ext_vector_type(8))) unsigned short u16x8;
typedef __attribute__((ext_vector_type(8))) short bf16x8;   // 8 bf16 = 4 VGPRs
typedef __attribute__((ext_vector_type(4))) float f32x4;

#define LORA_SCALE 2.0f   // ALPHA/RANK = 32/16

// round-to-nearest-even f32 -> bf16
__device__ __forceinline__ u16 f2bf(float f) {
  unsigned u = __builtin_bit_cast(unsigned, f);
  u += 0x7FFFu + ((u >> 16) & 1u);
  return (u16)(u >> 16);
}

#define GLOAD16(g, l) __builtin_amdgcn_global_load_lds(                        \
    (const __attribute__((address_space(1))) void*)(g),                        \
    (__attribute__((address_space(3))) void*)(l), 16, 0, 0)

// ---------------------------------------------------------------------------
// Kernel 1: W_eff[n,k] = W[n,k] + SCALE * sum_r B[k,r]*A[r,n]  -> bf16
// ---------------------------------------------------------------------------
__global__ __launch_bounds__(256) void make_weff(
    const float* __restrict__ W, const float* __restrict__ B,
    const float* __restrict__ A, u16* __restrict__ Wb)
{
  __shared__ float sA[16][64];
  const int n0 = (blockIdx.x >> 4) * 64;
  const int k0 = (blockIdx.x & 15) * 256;
  const int t  = threadIdx.x;

  {
    const int r = t >> 4;
    const int j = (t & 15) * 4;
    const float4 v = *(const float4*)(A + (size_t)r * 4096 + n0 + j);
    sA[r][j + 0] = LORA_SCALE * v.x;
    sA[r][j + 1] = LORA_SCALE * v.y;
    sA[r][j + 2] = LORA_SCALE * v.z;
    sA[r][j + 3] = LORA_SCALE * v.w;
  }
  __syncthreads();

  const int tn = t >> 6;
  const int tk = t & 63;

  float bv[64];
  const float4* pb = (const float4*)(B + (size_t)(k0 + tk * 4) * 16);
#pragma unroll
  for (int q = 0; q < 16; ++q) {
    float4 v = pb[q];
    bv[q * 4 + 0] = v.x; bv[q * 4 + 1] = v.y;
    bv[q * 4 + 2] = v.z; bv[q * 4 + 3] = v.w;
  }

  for (int i = 0; i < 16; ++i) {
    const int n = n0 + tn * 16 + i;
    const float4 w4 = *(const float4*)(W + (size_t)n * 4096 + k0 + tk * 4);
    float acc[4] = {w4.x, w4.y, w4.z, w4.w};
#pragma unroll
    for (int j = 0; j < 4; ++j)
#pragma unroll
      for (int r = 0; r < 16; ++r)
        acc[j] += bv[j * 16 + r] * sA[r][tn * 16 + i];
    u16x4 o;
    o[0] = f2bf(acc[0]); o[1] = f2bf(acc[1]);
    o[2] = f2bf(acc[2]); o[3] = f2bf(acc[3]);
    *(u16x4*)(Wb + (size_t)n * 4096 + k0 + tk * 4) = o;
  }
}

// ---------------------------------------------------------------------------
// Kernel 2: x f32 -> bf16
// ---------------------------------------------------------------------------
__global__ __launch_bounds__(256) void cvt_x_kernel(
    const float* __restrict__ x, u16* __restrict__ xb, long n)
{
  long i0 = ((long)blockIdx.x * blockDim.x + threadIdx.x) * 8;
  long stride = (long)gridDim.x * blockDim.x * 8;
  for (long i = i0; i < n; i += stride) {
    float4 a = *(const float4*)(x + i);
    float4 b = *(const float4*)(x + i + 4);
    u16x8 o;
    o[0] = f2bf(a.x); o[1] = f2bf(a.y); o[2] = f2bf(a.z); o[3] = f2bf(a.w);
    o[4] = f2bf(b.x); o[5] = f2bf(b.y); o[6] = f2bf(b.z); o[7] = f2bf(b.w);
    *(u16x8*)(xb + i) = o;
  }
}

// ---------------------------------------------------------------------------
// Kernel 3: 256x256 tile, BK=32, 512 thr (8 waves 2Mx4N, 128x64 per wave),
// TRIPLE-buffered LDS (3 x 32KB), counted vmcnt(4), XOR-swizzled LDS
// (pre-swizzled source), XCD-bijective block swizzle.
//
// R4 change (single variable): removed the 3 mid-tile barriers. R3's lockstep
// {reads -> barrier -> MFMA -> barrier} serialized the LDS-drain head with the
// MFMA tail across all 8 waves (measured 2531 cyc/tile vs ~1650 overlap bound).
// Correctness needs only ONE vmcnt(4)+barrier per tile:
//   (a) STAGE(tt+2) overwrites buf (tt-1)%3, whose readers all passed the
//       end-of-tile-(tt-1) barrier;
//   (b) every wave's vmcnt(4) precedes the end-of-tile barrier, so after it
//       ALL waves' tile-(tt+1) loads have landed.
// Within a tile waves now free-run: one wave's MFMA overlaps another's
// ds_read drain; setprio(1) keeps matrix-pipe waves prioritized (T5).
// ---------------------------------------------------------------------------
__global__ __launch_bounds__(512, 2) void gemm256(
    const u16* __restrict__ Xb, const u16* __restrict__ Wb,
    const float* __restrict__ bias, float* __restrict__ out)
{
  constexpr int K = 4096, N = 4096;
  constexpr int NT = K / 32;            // 128 K-tiles
  __shared__ char lds[3 * 32768];       // per buf: A 16KB @0, B 16KB @16384

  const int t = threadIdx.x;
  const int w = t >> 6, l = t & 63;
  const int wave_m = w >> 2, wave_n = w & 3;

  // XCD-bijective swizzle (512 % 8 == 0)
  const int bid = blockIdx.x;
  const int swz = (bid & 7) * 64 + (bid >> 3);
  const int tm = swz >> 4, tn = swz & 15;       // 32 x 16 tiles
  const int m0 = tm * 256, n0 = tn * 256;

  // ---- staging addressing (pre-swizzled global source, linear LDS dest) ----
  // LDS flat (row r, 16B-chunk c'):  r*64 + c'*16 ; content = global chunk c'^s(r),
  // s(r) = (r>>1)&3.  lane l -> r_local = l>>2, c' = l&3, source chunk = (l&3)^((l>>3)&3).
  const int lrow = l >> 2;
  const int lch  = ((l & 3) ^ ((l >> 3) & 3)) * 8;   // element offset in K
  const u16* gAs = Xb + (size_t)(m0 + w * 16 + lrow) * K + lch;
  const u16* gBs = Wb + (size_t)(n0 + w * 16 + lrow) * K + lch;
  char* ldsw = lds + w * 1024;                       // wave-uniform dest base

#define STAGE_A(tt, bb) do {                                                   \
    GLOAD16(gAs + (size_t)(tt) * 32,                  ldsw + (bb) * 32768);    \
    GLOAD16(gAs + (size_t)(tt) * 32 + 128 * (size_t)K, ldsw + (bb) * 32768 + 8192); \
  } while (0)
#define STAGE_B(tt, bb) do {                                                   \
    GLOAD16(gBs + (size_t)(tt) * 32,                  ldsw + (bb) * 32768 + 16384); \
    GLOAD16(gBs + (size_t)(tt) * 32 + 128 * (size_t)K, ldsw + (bb) * 32768 + 16384 + 8192); \
  } while (0)

  // ---- fragment read bases (swizzled chunk: fq ^ ((fr>>1)&3)) ----
  const int fr = l & 15, fq = l >> 4;
  const int coff = (fq ^ ((fr >> 1) & 3)) << 4;      // byte offset of chunk
  const char* pa0 = lds + (wave_m * 128 + fr) * 64 + coff;
  const char* pb0 = lds + 16384 + (wave_n * 64 + fr) * 64 + coff;

  f32x4 acc[8][4];
#pragma unroll
  for (int i = 0; i < 8; ++i)
#pragma unroll
    for (int j = 0; j < 4; ++j) acc[i][j] = (f32x4){0.f, 0.f, 0.f, 0.f};

  // ---- prologue: tiles 0,1 in flight; wait tile 0 ----
  STAGE_A(0, 0); STAGE_B(0, 0);
  STAGE_A(1, 1); STAGE_B(1, 1);
  asm volatile("s_waitcnt vmcnt(4)" ::: "memory");
  __builtin_amdgcn_s_barrier();

  int b = 0;
  for (int tt = 0; tt < NT; ++tt) {
    const char* pa = pa0 + b * 32768;
    const char* pb = pb0 + b * 32768;
    const int bs = (b == 2) ? 0 : b + 1;   // (tt+1)%3
    const int b2 = (b >= 1) ? b - 1 : 2;   // (tt+2)%3

    // ---------- phase A: rows 0-63 of this wave's 128 ----------
    bf16x8 bf[4], af[4];
#pragma unroll
    for (int nj = 0; nj < 4; ++nj)
      bf[nj] = *(const bf16x8*)(pb + nj * 1024);
#pragma unroll
    for (int mi = 0; mi < 4; ++mi)
      af[mi] = *(const bf16x8*)(pa + mi * 1024);
    if (tt + 2 < NT) STAGE_A(tt + 2, b2);
    __builtin_amdgcn_s_setprio(1);
#pragma unroll
    for (int mi = 0; mi < 4; ++mi)
#pragma unroll
      for (int nj = 0; nj < 4; ++nj)
        acc[mi][nj] = __builtin_amdgcn_mfma_f32_16x16x32_bf16(
            af[mi], bf[nj], acc[mi][nj], 0, 0, 0);
    __builtin_amdgcn_s_setprio(0);

    // ---------- phase B: rows 64-127 (B frags reused from regs) ----------
#pragma unroll
    for (int mi = 0; mi < 4; ++mi)
      af[mi] = *(const bf16x8*)(pa + 4096 + mi * 1024);
    if (tt + 2 < NT) STAGE_B(tt + 2, b2);
    __builtin_amdgcn_s_setprio(1);
#pragma unroll
    for (int mi = 0; mi < 4; ++mi)
#pragma unroll
      for (int nj = 0; nj < 4; ++nj)
        acc[4 + mi][nj] = __builtin_amdgcn_mfma_f32_16x16x32_bf16(
            af[mi], bf[nj], acc[4 + mi][nj], 0, 0, 0);
    __builtin_amdgcn_s_setprio(0);

    // one sync point per tile: force tile tt+1's loads landed (all waves),
    // then barrier so (a) rotation is safe and (b) cross-wave staging visible.
    if (tt + 2 < NT) { asm volatile("s_waitcnt vmcnt(4)" ::: "memory"); }
    else             { asm volatile("s_waitcnt vmcnt(0)" ::: "memory"); }
    __builtin_amdgcn_s_barrier();

    b = bs;
  }

  // ---- epilogue: bias + store (C/D layout: col=lane&15, row=(lane>>4)*4+i) ----
  float bvals[4];
#pragma unroll
  for (int nj = 0; nj < 4; ++nj)
    bvals[nj] = bias[n0 + wave_n * 64 + nj * 16 + fr];

#pragma unroll
  for (int ph = 0; ph < 2; ++ph)
#pragma unroll
    for (int mi = 0; mi < 4; ++mi)
#pragma unroll
      for (int i = 0; i < 4; ++i) {
        const int m = m0 + wave_m * 128 + ph * 64 + mi * 16 + fq * 4 + i;
        float* orow = out + (size_t)m * N + n0 + wave_n * 64 + fr;
#pragma unroll
        for (int nj = 0; nj < 4; ++nj)
          orow[nj * 16] = acc[ph * 4 + mi][nj][i] + bvals[nj];
      }
}

// ---------------------------------------------------------------------------
extern "C" void kernel_launch(void* const* d_in, const int* in_sizes, int n_in,
                              void* d_out, int out_size, void* d_ws, size_t ws_size,
                              hipStream_t stream) {
  const float* x    = (const float*)d_in[0];  // [4,2048,4096] -> [8192,4096]
  const float* W    = (const float*)d_in[1];  // [4096,4096] (n,k)
  const float* bias = (const float*)d_in[2];  // [4096]
  const float* B    = (const float*)d_in[3];  // [4096,16]
  const float* A    = (const float*)d_in[4];  // [16,4096]
  float* out = (float*)d_out;

  u16* Xb = (u16*)d_ws;                         // 8192*4096 bf16 = 64 MiB
  u16* Wb = Xb + (size_t)8192 * 4096;           // 4096*4096 bf16 = 32 MiB

  make_weff<<<dim3(1024), dim3(256), 0, stream>>>(W, B, A, Wb);
  cvt_x_kernel<<<dim3(2048), dim3(256), 0, stream>>>(x, Xb, (long)8192 * 4096);
  gemm256<<<dim3(512), dim3(512), 0, stream>>>(Xb, Wb, bias, out);
}

// Round 6
// 492.398 us; speedup vs baseline: 1.1998x; 1.0367x over previous
//
#include <hip/hip_runtime.h>

// ---------- types ----------
typedef unsigned short u16;
typedef __attribute__((ext_vector_type(4))) unsigned short u16x4;
typedef __attribute__((ext_vector_type(8))) unsigned short u16x8;
typedef __attribute__((ext_vector_type(8))) short bf16x8;   // 8 bf16 = 4 VGPRs
typedef __attribute__((ext_vector_type(4))) float f32x4;

#define LORA_SCALE 2.0f   // ALPHA/RANK = 32/16

// round-to-nearest-even f32 -> bf16
__device__ __forceinline__ u16 f2bf(float f) {
  unsigned u = __builtin_bit_cast(unsigned, f);
  u += 0x7FFFu + ((u >> 16) & 1u);
  return (u16)(u >> 16);
}

#define GLOAD16(g, l) __builtin_amdgcn_global_load_lds(                        \
    (const __attribute__((address_space(1))) void*)(g),                        \
    (__attribute__((address_space(3))) void*)(l), 16, 0, 0)

// ---------------------------------------------------------------------------
// Kernel 1 (fused prep): blocks [0,1024): W_eff = W + SCALE*B@A -> bf16
//                        blocks [1024,3072): x f32 -> bf16
// Both paths identical to the R4-verified kernels; fusion saves a launch and
// overlaps the two memory-bound phases.
// ---------------------------------------------------------------------------
__global__ __launch_bounds__(256) void prep(
    const float* __restrict__ W, const float* __restrict__ B,
    const float* __restrict__ A, u16* __restrict__ Wb,
    const float* __restrict__ x, u16* __restrict__ xb, long n)
{
  if (blockIdx.x < 1024) {
    // ---- make_weff path ----
    __shared__ float sA[16][64];
    const int n0 = ((int)blockIdx.x >> 4) * 64;
    const int k0 = ((int)blockIdx.x & 15) * 256;
    const int t  = threadIdx.x;

    {
      const int r = t >> 4;
      const int j = (t & 15) * 4;
      const float4 v = *(const float4*)(A + (size_t)r * 4096 + n0 + j);
      sA[r][j + 0] = LORA_SCALE * v.x;
      sA[r][j + 1] = LORA_SCALE * v.y;
      sA[r][j + 2] = LORA_SCALE * v.z;
      sA[r][j + 3] = LORA_SCALE * v.w;
    }
    __syncthreads();

    const int tn = t >> 6;
    const int tk = t & 63;

    float bv[64];
    const float4* pb = (const float4*)(B + (size_t)(k0 + tk * 4) * 16);
#pragma unroll
    for (int q = 0; q < 16; ++q) {
      float4 v = pb[q];
      bv[q * 4 + 0] = v.x; bv[q * 4 + 1] = v.y;
      bv[q * 4 + 2] = v.z; bv[q * 4 + 3] = v.w;
    }

    for (int i = 0; i < 16; ++i) {
      const int nn = n0 + tn * 16 + i;
      const float4 w4 = *(const float4*)(W + (size_t)nn * 4096 + k0 + tk * 4);
      float acc[4] = {w4.x, w4.y, w4.z, w4.w};
#pragma unroll
      for (int j = 0; j < 4; ++j)
#pragma unroll
        for (int r = 0; r < 16; ++r)
          acc[j] += bv[j * 16 + r] * sA[r][tn * 16 + i];
      u16x4 o;
      o[0] = f2bf(acc[0]); o[1] = f2bf(acc[1]);
      o[2] = f2bf(acc[2]); o[3] = f2bf(acc[3]);
      *(u16x4*)(Wb + (size_t)nn * 4096 + k0 + tk * 4) = o;
    }
  } else {
    // ---- cvt_x path ----
    const long cb = (long)blockIdx.x - 1024;          // 0..2047
    long i0 = (cb * blockDim.x + threadIdx.x) * 8;
    long stride = (long)2048 * blockDim.x * 8;
    for (long i = i0; i < n; i += stride) {
      float4 a = *(const float4*)(x + i);
      float4 b = *(const float4*)(x + i + 4);
      u16x8 o;
      o[0] = f2bf(a.x); o[1] = f2bf(a.y); o[2] = f2bf(a.z); o[3] = f2bf(a.w);
      o[4] = f2bf(b.x); o[5] = f2bf(b.y); o[6] = f2bf(b.z); o[7] = f2bf(b.w);
      *(u16x8*)(xb + i) = o;
    }
  }
}

// ---------------------------------------------------------------------------
// Kernel 2: GEMM 256x256 tile, BK=32, 8 waves (2Mx4N, 128x64/wave), triple-
// buffered LDS, counted vmcnt(4), XOR-swizzled LDS, XCD-bijective swizzle.
//
// R5 change: register-level fragment pipelining (sync skeleton IDENTICAL to
// R4 — same STAGE schedule, same single vmcnt+barrier per tile, same buffer
// rotation). Per tile:
//   1. issue afB reads (this tile)          — drain covered by MFMA-A
//   2. STAGE_A(tt+2)
//   3. MFMA-A (bf, afA from regs — read one full tile ago, wait-free)
//   4. STAGE_B(tt+2)
//   5. MFMA-B (bf, afB)
//   6. vmcnt(4) + s_barrier                 — tile tt+1 landed + visible
//   7. issue bf/afA reads for tile tt+1     — consumed next iter step 3
// All reads of buf b are consumed by MFMAs BEFORE the tile's barrier (so they
// complete before it); buf b's next overwrite (STAGE(tt+3)) issues after it.
// ---------------------------------------------------------------------------
__global__ __launch_bounds__(512, 2) void gemm256(
    const u16* __restrict__ Xb, const u16* __restrict__ Wb,
    const float* __restrict__ bias, float* __restrict__ out)
{
  constexpr int K = 4096, N = 4096;
  constexpr int NT = K / 32;            // 128 K-tiles
  __shared__ char lds[3 * 32768];       // per buf: A 16KB @0, B 16KB @16384

  const int t = threadIdx.x;
  const int w = t >> 6, l = t & 63;
  const int wave_m = w >> 2, wave_n = w & 3;

  // XCD-bijective swizzle (512 % 8 == 0)
  const int bid = blockIdx.x;
  const int swz = (bid & 7) * 64 + (bid >> 3);
  const int tm = swz >> 4, tn = swz & 15;       // 32 x 16 tiles
  const int m0 = tm * 256, n0 = tn * 256;

  // ---- staging addressing (pre-swizzled global source, linear LDS dest) ----
  const int lrow = l >> 2;
  const int lch  = ((l & 3) ^ ((l >> 3) & 3)) * 8;   // element offset in K
  const u16* gAs = Xb + (size_t)(m0 + w * 16 + lrow) * K + lch;
  const u16* gBs = Wb + (size_t)(n0 + w * 16 + lrow) * K + lch;
  char* ldsw = lds + w * 1024;                       // wave-uniform dest base

#define STAGE_A(tt, bb) do {                                                   \
    GLOAD16(gAs + (size_t)(tt) * 32,                  ldsw + (bb) * 32768);    \
    GLOAD16(gAs + (size_t)(tt) * 32 + 128 * (size_t)K, ldsw + (bb) * 32768 + 8192); \
  } while (0)
#define STAGE_B(tt, bb) do {                                                   \
    GLOAD16(gBs + (size_t)(tt) * 32,                  ldsw + (bb) * 32768 + 16384); \
    GLOAD16(gBs + (size_t)(tt) * 32 + 128 * (size_t)K, ldsw + (bb) * 32768 + 16384 + 8192); \
  } while (0)

  // ---- fragment read bases (swizzled chunk: fq ^ ((fr>>1)&3)) ----
  const int fr = l & 15, fq = l >> 4;
  const int coff = (fq ^ ((fr >> 1) & 3)) << 4;      // byte offset of chunk
  const char* pa0 = lds + (wave_m * 128 + fr) * 64 + coff;
  const char* pb0 = lds + 16384 + (wave_n * 64 + fr) * 64 + coff;

  f32x4 acc[8][4];
#pragma unroll
  for (int i = 0; i < 8; ++i)
#pragma unroll
    for (int j = 0; j < 4; ++j) acc[i][j] = (f32x4){0.f, 0.f, 0.f, 0.f};

  // ---- prologue: tiles 0,1 in flight; wait tile 0; preload tile-0 frags ----
  STAGE_A(0, 0); STAGE_B(0, 0);
  STAGE_A(1, 1); STAGE_B(1, 1);
  asm volatile("s_waitcnt vmcnt(4)" ::: "memory");
  __builtin_amdgcn_s_barrier();

  bf16x8 bf[4], afA[4];
#pragma unroll
  for (int nj = 0; nj < 4; ++nj) bf[nj]  = *(const bf16x8*)(pb0 + nj * 1024);
#pragma unroll
  for (int mi = 0; mi < 4; ++mi) afA[mi] = *(const bf16x8*)(pa0 + mi * 1024);

  int b = 0;
  for (int tt = 0; tt < NT; ++tt) {
    const char* pa = pa0 + b * 32768;
    const int bs = (b == 2) ? 0 : b + 1;   // (tt+1)%3
    const int b2 = (b >= 1) ? b - 1 : 2;   // (tt+2)%3

    // 1. afB reads for THIS tile (drain covered by MFMA-A)
    bf16x8 afB[4];
#pragma unroll
    for (int mi = 0; mi < 4; ++mi)
      afB[mi] = *(const bf16x8*)(pa + 4096 + mi * 1024);

    // 2. prefetch stage A
    if (tt + 2 < NT) STAGE_A(tt + 2, b2);

    // 3. MFMA-A on regs read one tile ago (wait-free)
    __builtin_amdgcn_s_setprio(1);
#pragma unroll
    for (int mi = 0; mi < 4; ++mi)
#pragma unroll
      for (int nj = 0; nj < 4; ++nj)
        acc[mi][nj] = __builtin_amdgcn_mfma_f32_16x16x32_bf16(
            afA[mi], bf[nj], acc[mi][nj], 0, 0, 0);
    __builtin_amdgcn_s_setprio(0);

    // 4. prefetch stage B
    if (tt + 2 < NT) STAGE_B(tt + 2, b2);

    // 5. MFMA-B (afB drained by compiler-counted lgkmcnt)
    __builtin_amdgcn_s_setprio(1);
#pragma unroll
    for (int mi = 0; mi < 4; ++mi)
#pragma unroll
      for (int nj = 0; nj < 4; ++nj)
        acc[4 + mi][nj] = __builtin_amdgcn_mfma_f32_16x16x32_bf16(
            afB[mi], bf[nj], acc[4 + mi][nj], 0, 0, 0);
    __builtin_amdgcn_s_setprio(0);

    // 6. one sync point per tile: tile tt+1 landed (all waves) + visible
    if (tt + 2 < NT) { asm volatile("s_waitcnt vmcnt(4)" ::: "memory"); }
    else             { asm volatile("s_waitcnt vmcnt(0)" ::: "memory"); }
    __builtin_amdgcn_s_barrier();

    // 7. read next tile's bf/afA (consumed next iteration -> auto-counted wait)
    if (tt + 1 < NT) {
      const char* pan = pa0 + bs * 32768;
      const char* pbn = pb0 + bs * 32768;
#pragma unroll
      for (int nj = 0; nj < 4; ++nj) bf[nj]  = *(const bf16x8*)(pbn + nj * 1024);
#pragma unroll
      for (int mi = 0; mi < 4; ++mi) afA[mi] = *(const bf16x8*)(pan + mi * 1024);
    }

    b = bs;
  }

  // ---- epilogue: bias + store (C/D layout: col=lane&15, row=(lane>>4)*4+i) ----
  float bvals[4];
#pragma unroll
  for (int nj = 0; nj < 4; ++nj)
    bvals[nj] = bias[n0 + wave_n * 64 + nj * 16 + fr];

#pragma unroll
  for (int ph = 0; ph < 2; ++ph)
#pragma unroll
    for (int mi = 0; mi < 4; ++mi)
#pragma unroll
      for (int i = 0; i < 4; ++i) {
        const int m = m0 + wave_m * 128 + ph * 64 + mi * 16 + fq * 4 + i;
        float* orow = out + (size_t)m * N + n0 + wave_n * 64 + fr;
#pragma unroll
        for (int nj = 0; nj < 4; ++nj)
          orow[nj * 16] = acc[ph * 4 + mi][nj][i] + bvals[nj];
      }
}

// ---------------------------------------------------------------------------
extern "C" void kernel_launch(void* const* d_in, const int* in_sizes, int n_in,
                              void* d_out, int out_size, void* d_ws, size_t ws_size,
                              hipStream_t stream) {
  const float* x    = (const float*)d_in[0];  // [4,2048,4096] -> [8192,4096]
  const float* W    = (const float*)d_in[1];  // [4096,4096] (n,k)
  const float* bias = (const float*)d_in[2];  // [4096]
  const float* B    = (const float*)d_in[3];  // [4096,16]
  const float* A    = (const float*)d_in[4];  // [16,4096]
  float* out = (float*)d_out;

  u16* Xb = (u16*)d_ws;                         // 8192*4096 bf16 = 64 MiB
  u16* Wb = Xb + (size_t)8192 * 4096;           // 4096*4096 bf16 = 32 MiB

  prep<<<dim3(3072), dim3(256), 0, stream>>>(W, B, A, Wb, x, Xb,
                                             (long)8192 * 4096);
  gemm256<<<dim3(512), dim3(512), 0, stream>>>(Xb, Wb, bias, out);
}